// Round 7
// baseline (90.096 us; speedup 1.0000x reference)
//
#include <hip/hip_runtime.h>
#include <hip/hip_bf16.h>

// Problem: B=4096, IN=1024, H=1024.
// pre = x@U^T + h@W^T + Ub -> gates -> h_t, c_t   (fused after convert)
// GEMM: M=4096 (batch), N=4096 (4H permuted), K=2048 (IN+H concat)
//
// B-permutation: permuted column p = bn*256 + wn*64 + g*16 + c corresponds to
// gate g (f,i,o,g), hidden j = bn*64 + wn*16 + c. With the verified C/D
// layout (col = lane&15), wave fragment n == gate n at the SAME lane (same j),
// so the LSTM gate math is lane-local in the GEMM epilogue.

#define BATCH 4096
#define HID   1024
#define KDIM  2048

// 256x256 tile, BK=32, 4-slot LDS ring, 8 waves (2Mx4N), 512 threads.
#define BM 256
#define BN 256
#define BK 32
#define NT (KDIM / BK)          // 64 K-tiles
#define SLOT_E (BM * BK)        // 8192 bf16 elements per A/B slot

typedef __bf16 bf16x8 __attribute__((ext_vector_type(8)));
typedef float  f32x4  __attribute__((ext_vector_type(4)));

__device__ __forceinline__ void async_load16(const void* g, void* l) {
    __builtin_amdgcn_global_load_lds(
        (const __attribute__((address_space(1))) void*)g,
        (__attribute__((address_space(3))) void*)l,
        16, 0, 0);
}

__device__ __forceinline__ float sigmoidf_(float v) {
    return 1.0f / (1.0f + __expf(-v));
}
__device__ __forceinline__ float tanhf_(float v) {
    return 1.0f - 2.0f / (__expf(2.0f * v) + 1.0f);
}

// ---------------------------------------------------------------------------
// Kernel 1: f32 -> bf16 conversion + K-concat; B side also gate-permuted.
// ---------------------------------------------------------------------------
__global__ __launch_bounds__(256) void convert_kernel(
    const float* __restrict__ x, const float* __restrict__ h,
    const float* __restrict__ U, const float* __restrict__ W,
    __hip_bfloat16* __restrict__ Acat, __hip_bfloat16* __restrict__ Bcat)
{
    const int CH_PER_MAT = (4096 * KDIM) / 8;
    int idx = blockIdx.x * blockDim.x + threadIdx.x;
    bool isB = idx >= CH_PER_MAT;
    int c = isB ? (idx - CH_PER_MAT) : idx;
    int row  = c >> 8;                 // dest row (permuted for B)
    int col  = (c & 255) << 3;
    int srow = row;
    if (isB) {
        // p = bn*256 + wn*64 + g*16 + cc  ->  orig row = g*1024 + (bn*64+wn*16+cc)
        int g  = (row >> 4) & 3;
        int j  = ((row >> 8) << 6) + (((row >> 6) & 3) << 4) + (row & 15);
        srow = g * 1024 + j;
    }
    const float* src;
    if (col < 1024) src = (isB ? U : x) + (size_t)srow * 1024 + col;
    else            src = (isB ? W : h) + (size_t)srow * 1024 + (col - 1024);
    float4 v0 = *(const float4*)(src);
    float4 v1 = *(const float4*)(src + 4);
    __hip_bfloat16 tmp[8];
    tmp[0] = __float2bfloat16(v0.x); tmp[1] = __float2bfloat16(v0.y);
    tmp[2] = __float2bfloat16(v0.z); tmp[3] = __float2bfloat16(v0.w);
    tmp[4] = __float2bfloat16(v1.x); tmp[5] = __float2bfloat16(v1.y);
    tmp[6] = __float2bfloat16(v1.z); tmp[7] = __float2bfloat16(v1.w);
    __hip_bfloat16* dst = (isB ? Bcat : Acat) + (size_t)row * KDIM + col;
    *(bf16x8*)dst = *(const bf16x8*)tmp;
}

// ---------------------------------------------------------------------------
// Kernel 2: fused bf16 GEMM + LSTM gates.
// Round-7 change: L2-locality block map. Dispatch round-robins blockIdx
// across XCDs (xcd = wg & 7); give each XCD a 4bm x 8bn RECTANGLE of the
// 16x16 tile grid instead of 2 x 16. Per-XCD per-K-step working set drops
// from 18 to 12 panel-slices (768 KB over the 4-deep ring -> fits 4 MB L2);
// compulsory L2-fill drops 144 -> 96 MB. Map is bijective:
//   bm = (xcd>>1)*4 + (i>>3), bn = (xcd&1)*8 + (i&7),  i = wg>>3.
// K-loop body/schedule identical to round 6.
// ---------------------------------------------------------------------------
__global__ __launch_bounds__(512, 1) void gemm_lstm_kernel(
    const __hip_bfloat16* __restrict__ A,   // [4096][2048]
    const __hip_bfloat16* __restrict__ Bm,  // [4096][2048] gate-permuted
    const float* __restrict__ Ub,           // [4096]
    const float* __restrict__ c_prev,       // [4096][1024]
    float* __restrict__ out)                // h_t [4096][1024] ++ c_t [4096][1024]
{
    __shared__ __align__(16) __hip_bfloat16 smem[4 * 2 * SLOT_E];  // 128 KB

    const int tid  = threadIdx.x;
    const int lane = tid & 63;
    const int wid  = tid >> 6;     // 0..7
    const int wm   = wid >> 2;     // 0..1  (M half)
    const int wn   = wid & 3;      // 0..3  (N quarter)

    // L2-locality map: each XCD owns a 4x8 rectangle of the 16x16 block grid.
    int wg  = blockIdx.x;
    const int xcd = wg & 7;
    const int i_  = wg >> 3;
    const int bm = ((xcd >> 1) << 2) + (i_ >> 3);
    const int bn = ((xcd & 1) << 3) + (i_ & 7);

    const __hip_bfloat16* Ab = A  + (size_t)bm * BM * KDIM;
    const __hip_bfloat16* Bb = Bm + (size_t)bn * BN * KDIM;

    // ds_read fragment addressing (T2-swizzled).
    const int frow = lane & 15;
    const int sp8  = (((lane >> 4) ^ ((frow >> 1) & 3)) << 3);
    const int arow = wm * 128 + frow;
    const int brow = wn * 64  + frow;

    // Staging: 1024 16B-chunks/matrix/K-tile; linear LDS dest, pre-swizzled
    // global source (both-sides-or-neither rule).
    const int c0 = tid,        c1 = 512 + tid;
    const int r0 = c0 >> 2,    r1 = c1 >> 2;
    const int g0 = ((c0 & 3) ^ ((r0 >> 1) & 3)) << 3;
    const int g1 = ((c1 & 3) ^ ((r1 >> 1) & 3)) << 3;
    const size_t ga0 = (size_t)r0 * KDIM + g0;
    const size_t ga1 = (size_t)r1 * KDIM + g1;
    const int l0 = c0 << 3,    l1 = c1 << 3;

    f32x4 acc[8][4] = {};
    // two named fragment sets (ping-pong; never runtime-indexed)
    bf16x8 arA[4], ar2A[4], brA[4];
    bf16x8 arB[4], ar2B[4], brB[4];

#define STAGE_A(kt, slot) do { \
    int _ko = (kt) * BK; unsigned _b = (unsigned)((slot) * 2 + 0) * SLOT_E; \
    async_load16(Ab + ga0 + _ko, &smem[_b + l0]); \
    async_load16(Ab + ga1 + _ko, &smem[_b + l1]); } while (0)
#define STAGE_B(kt, slot) do { \
    int _ko = (kt) * BK; unsigned _b = (unsigned)((slot) * 2 + 1) * SLOT_E; \
    async_load16(Bb + ga0 + _ko, &smem[_b + l0]); \
    async_load16(Bb + ga1 + _ko, &smem[_b + l1]); } while (0)

    // prefetch all 12 fragments of K-tile kt into the named set (data landed)
#define PREFETCH(kt, AR, AR2, BR) do { \
    const unsigned _ab = (unsigned)(((kt) & 3) * 2 + 0) * SLOT_E; \
    const unsigned _bb = (unsigned)(((kt) & 3) * 2 + 1) * SLOT_E; \
    _Pragma("unroll") \
    for (int m = 0; m < 4; ++m) \
        AR[m]  = *(const bf16x8*)&smem[_ab + (unsigned)((arow + m * 16) * BK) + sp8]; \
    _Pragma("unroll") \
    for (int m = 0; m < 4; ++m) \
        AR2[m] = *(const bf16x8*)&smem[_ab + (unsigned)((arow + 64 + m * 16) * BK) + sp8]; \
    _Pragma("unroll") \
    for (int n = 0; n < 4; ++n) \
        BR[n]  = *(const bf16x8*)&smem[_bb + (unsigned)((brow + n * 16) * BK) + sp8]; \
    } while (0)

#define MFMA_TILE(AR, AR2, BR) do { \
    __builtin_amdgcn_s_setprio(1); \
    _Pragma("unroll") \
    for (int m = 0; m < 4; ++m) \
        _Pragma("unroll") \
        for (int n = 0; n < 4; ++n) \
            acc[m][n] = __builtin_amdgcn_mfma_f32_16x16x32_bf16(AR[m], BR[n], acc[m][n], 0, 0, 0); \
    _Pragma("unroll") \
    for (int m = 0; m < 4; ++m) \
        _Pragma("unroll") \
        for (int n = 0; n < 4; ++n) \
            acc[m + 4][n] = __builtin_amdgcn_mfma_f32_16x16x32_bf16(AR2[m], BR[n], acc[m + 4][n], 0, 0, 0); \
    __builtin_amdgcn_s_setprio(0); \
    } while (0)

    // ---- prologue: stage K0..K2; vmcnt(8) completes K0 (4 oldest of 12) ----
    STAGE_A(0, 0); STAGE_B(0, 0);
    STAGE_A(1, 1); STAGE_B(1, 1);
    STAGE_A(2, 2); STAGE_B(2, 2);
    asm volatile("s_waitcnt vmcnt(8)" ::: "memory");
    __builtin_amdgcn_s_barrier();
    PREFETCH(0, arA, ar2A, brA);

#pragma unroll 1
    for (int i = 0; i < NT / 2; ++i) {
        const int t0 = 2 * i, t1 = 2 * i + 1;
        {   // ---- tile t0: consume set A, prefetch set B for t1 ----
            int tp = t0 + 3; if (tp > NT - 1) tp = NT - 1;
            const int ps = (t0 + 3) & 3;
            STAGE_A(tp, ps);
            STAGE_B(tp, ps);
            asm volatile("s_waitcnt vmcnt(8)" ::: "memory");  // K(t0+1) landed
            PREFETCH(t1, arB, ar2B, brB);     // t1 <= 63 always
            MFMA_TILE(arA, ar2A, brA);
            __builtin_amdgcn_s_barrier();
        }
        {   // ---- tile t1: consume set B, prefetch set A for t1+1 ----
            int tp = t1 + 3; if (tp > NT - 1) tp = NT - 1;
            const int ps = (t1 + 3) & 3;
            STAGE_A(tp, ps);
            STAGE_B(tp, ps);
            asm volatile("s_waitcnt vmcnt(8)" ::: "memory");  // K(t1+1) landed
            int tn = (t1 + 1 <= NT - 1) ? (t1 + 1) : (NT - 1); // i=31: re-read K63 (unused)
            PREFETCH(tn, arA, ar2A, brA);
            MFMA_TILE(arB, ar2B, brB);
            __builtin_amdgcn_s_barrier();
        }
    }
#undef STAGE_A
#undef STAGE_B
#undef PREFETCH
#undef MFMA_TILE

    // ---- fused epilogue: gates lane-local thanks to B permutation ----
    const int j = bn * 64 + wn * 16 + (lane & 15);
    const float bf_ = Ub[j];
    const float bi_ = Ub[1024 + j];
    const float bo_ = Ub[2048 + j];
    const float bg_ = Ub[3072 + j];
    const int row0 = bm * BM + wm * 128 + ((lane >> 4) << 2);

    // batch all c_prev loads first (hide latency), then math + stores
    float cp[8][4];
#pragma unroll
    for (int m = 0; m < 8; ++m)
#pragma unroll
        for (int r = 0; r < 4; ++r)
            cp[m][r] = c_prev[(size_t)(row0 + m * 16 + r) * HID + j];

#pragma unroll
    for (int m = 0; m < 8; ++m) {
#pragma unroll
        for (int r = 0; r < 4; ++r) {
            const int row = row0 + m * 16 + r;
            const float f  = sigmoidf_(acc[m][0][r] + bf_);
            const float it = sigmoidf_(acc[m][1][r] + bi_);
            const float o  = sigmoidf_(acc[m][2][r] + bo_);
            const float gg = tanhf_(acc[m][3][r] + bg_);
            const float cv = f * cp[m][r] + it * gg;
            const float hv = o * tanhf_(cv);
            out[(size_t)row * HID + j] = hv;
            out[(size_t)BATCH * HID + (size_t)row * HID + j] = cv;
        }
    }
}

// ---------------------------------------------------------------------------
extern "C" void kernel_launch(void* const* d_in, const int* in_sizes, int n_in,
                              void* d_out, int out_size, void* d_ws, size_t ws_size,
                              hipStream_t stream) {
    const float* x      = (const float*)d_in[0];
    const float* h_prev = (const float*)d_in[1];
    const float* c_prev = (const float*)d_in[2];
    const float* U_w    = (const float*)d_in[3];
    const float* U_b    = (const float*)d_in[4];
    const float* W_w    = (const float*)d_in[5];
    float* out = (float*)d_out;

    char* ws = (char*)d_ws;
    __hip_bfloat16* Acat = (__hip_bfloat16*)ws;                      // 16 MB
    __hip_bfloat16* Bcat = (__hip_bfloat16*)(ws + (16u << 20));      // 16 MB

    convert_kernel<<<8192, 256, 0, stream>>>(x, h_prev, U_w, W_w, Acat, Bcat);
    gemm_lstm_kernel<<<256, 512, 0, stream>>>(Acat, Bcat, U_b, c_prev, out);
}

// Round 8
// 83.616 us; speedup vs baseline: 1.0775x; 1.0775x over previous
//
#include <hip/hip_runtime.h>
#include <hip/hip_bf16.h>

// Problem: B=4096, IN=1024, H=1024.
// pre = x@U^T + h@W^T + Ub -> gates -> h_t, c_t   (fused after convert)
// GEMM: M=4096 (batch), N=4096 (4H permuted), K=2048 (IN+H concat)
//
// Round-8: full 8-phase deep-pipelined schedule (m201 template adapted).
//   BK=64, 2 LDS buffers of {A[2x128x64] | B[2x128x64]} bf16 = 128 KB.
//   Quad stream q = 4t + j, j in {(mh0,kk0),(mh0,kk1),(mh1,kk0),(mh1,kk1)};
//   slot s loads quad s, MFMAs quad s-1. Iter i = phases 1..8 = slots 8i+1..8i+8,
//   K-tiles ta=2i (buf0), tb=2i+1 (buf1).
//   Stage slots: ph1:A(tb)h1  ph2:B(c)h0 ph3:B(c)h1 ph4:A(c)h0 ph5:A(c)h1
//                ph6:B(d)h0 ph7:B(d)h1 ph8:A(d)h0      (c=2i+2->buf0, d=2i+3->buf1)
//   vmcnt(4) at ph3 (confirms tb fully landed before ph4 reads buf1) and
//   ph7 (confirms c landed before ph8 reads buf0). lgkmcnt(0) end-drain at
//   odd phases => any region's reads are drained >=1 barrier before its restage.
//   i=15: c,d source-clamped to t=31 (dest regions follow schedule; values
//   only touched by the final dummy loads at ph8, which are never used).

#define BATCH 4096
#define HID   1024
#define KDIM  2048

#define BM 256
#define BN 256
#define BK 64
#define NITER (KDIM / (2 * BK))   // 16

typedef __bf16 bf16x8 __attribute__((ext_vector_type(8)));
typedef float  f32x4  __attribute__((ext_vector_type(4)));

__device__ __forceinline__ void async_load16(const void* g, void* l) {
    __builtin_amdgcn_global_load_lds(
        (const __attribute__((address_space(1))) void*)g,
        (__attribute__((address_space(3))) void*)l,
        16, 0, 0);
}

__device__ __forceinline__ float sigmoidf_(float v) {
    return 1.0f / (1.0f + __expf(-v));
}
__device__ __forceinline__ float tanhf_(float v) {
    return 1.0f - 2.0f / (__expf(2.0f * v) + 1.0f);
}

// ---------------------------------------------------------------------------
// Kernel 1: f32 -> bf16 conversion + K-concat; B side gate-permuted. (as r7)
// ---------------------------------------------------------------------------
__global__ __launch_bounds__(256) void convert_kernel(
    const float* __restrict__ x, const float* __restrict__ h,
    const float* __restrict__ U, const float* __restrict__ W,
    __hip_bfloat16* __restrict__ Acat, __hip_bfloat16* __restrict__ Bcat)
{
    const int CH_PER_MAT = (4096 * KDIM) / 8;
    int idx = blockIdx.x * blockDim.x + threadIdx.x;
    bool isB = idx >= CH_PER_MAT;
    int c = isB ? (idx - CH_PER_MAT) : idx;
    int row  = c >> 8;
    int col  = (c & 255) << 3;
    int srow = row;
    if (isB) {
        int g  = (row >> 4) & 3;
        int j  = ((row >> 8) << 6) + (((row >> 6) & 3) << 4) + (row & 15);
        srow = g * 1024 + j;
    }
    const float* src;
    if (col < 1024) src = (isB ? U : x) + (size_t)srow * 1024 + col;
    else            src = (isB ? W : h) + (size_t)srow * 1024 + (col - 1024);
    float4 v0 = *(const float4*)(src);
    float4 v1 = *(const float4*)(src + 4);
    __hip_bfloat16 tmp[8];
    tmp[0] = __float2bfloat16(v0.x); tmp[1] = __float2bfloat16(v0.y);
    tmp[2] = __float2bfloat16(v0.z); tmp[3] = __float2bfloat16(v0.w);
    tmp[4] = __float2bfloat16(v1.x); tmp[5] = __float2bfloat16(v1.y);
    tmp[6] = __float2bfloat16(v1.z); tmp[7] = __float2bfloat16(v1.w);
    __hip_bfloat16* dst = (isB ? Bcat : Acat) + (size_t)row * KDIM + col;
    *(bf16x8*)dst = *(const bf16x8*)tmp;
}

// ---------------------------------------------------------------------------
// Kernel 2: fused bf16 GEMM + LSTM gates, 8-phase schedule.
// ---------------------------------------------------------------------------
__global__ __launch_bounds__(512, 1) void gemm_lstm_kernel(
    const __hip_bfloat16* __restrict__ A,   // [4096][2048]
    const __hip_bfloat16* __restrict__ Bm,  // [4096][2048] gate-permuted
    const float* __restrict__ Ub,           // [4096]
    const float* __restrict__ c_prev,       // [4096][1024]
    float* __restrict__ out)                // h_t ++ c_t
{
    __shared__ __align__(16) unsigned char smem[131072];  // 2 bufs x 64 KB

    const int tid  = threadIdx.x;
    const int lane = tid & 63;
    const int wid  = tid >> 6;
    const int wm   = wid >> 2;     // 0..1
    const int wn   = wid & 3;      // 0..3

    // L2-locality map (r7): each XCD owns a 4x8 rectangle of the 16x16 grid.
    int wg  = blockIdx.x;
    const int xcd = wg & 7;
    const int i_  = wg >> 3;
    const int bm = ((xcd >> 1) << 2) + (i_ >> 3);
    const int bn = ((xcd & 1) << 3) + (i_ & 7);

    const __hip_bfloat16* Ab = A  + (size_t)bm * BM * KDIM;
    const __hip_bfloat16* Bb = Bm + (size_t)bn * BN * KDIM;

    // ds_read addressing: half-tile [128 rows][64 cols] bf16, 8 x 16B slots/row.
    // swizzle: phys_slot = logical_slot ^ ((row>>1)&7); row&~15 doesn't affect it.
    const int frow = lane & 15;
    const int kq   = lane >> 4;                       // 0..3
    const int esw  = (frow >> 1) & 7;
    const unsigned xs0 = (unsigned)((kq ^ esw) << 4); // kk=0 slot byte
    const unsigned xs1 = xs0 ^ 64u;                   // kk=1
    const unsigned wmBase = (unsigned)wm * 16384u;    // A-half = wm
    const unsigned bnBase = (unsigned)(wn >> 1) * 16384u;
    const unsigned bnRow  = (unsigned)(wn & 1) * 64u;

    // staging: 1024 chunks/half-tile; thread stages ch0=tid, ch1=512+tid.
    // linear LDS dest (wave-uniform base + lane*16); global source pre-swizzled.
    const int ch0 = tid,           ch1 = 512 + tid;
    const int sr0 = ch0 >> 3,      sr1 = ch1 >> 3;
    const int sc0 = ((ch0 & 7) ^ ((sr0 >> 1) & 7)) << 3;
    const int sc1 = ((ch1 & 7) ^ ((sr1 >> 1) & 7)) << 3;
    const size_t ga0 = (size_t)sr0 * KDIM + sc0;
    const size_t ga1 = (size_t)sr1 * KDIM + sc1;

    f32x4 acc[8][4] = {};
    bf16x8 arE[4], arO[4], brE[4], brO[4];

#define RD16(B) (*(const bf16x8*)(smem + (B)))
#define LDA4(SET, BUFB, MH, XS) do { \
    const unsigned _b = (BUFB) + wmBase; \
    SET[0] = RD16(_b + (unsigned)((MH)*64 +  0 + frow)*128u + (XS)); \
    SET[1] = RD16(_b + (unsigned)((MH)*64 + 16 + frow)*128u + (XS)); \
    SET[2] = RD16(_b + (unsigned)((MH)*64 + 32 + frow)*128u + (XS)); \
    SET[3] = RD16(_b + (unsigned)((MH)*64 + 48 + frow)*128u + (XS)); } while (0)
#define LDB4(SET, BUFB, XS) do { \
    const unsigned _b = (BUFB) + 32768u + bnBase; \
    SET[0] = RD16(_b + (bnRow +  0 + frow)*128u + (XS)); \
    SET[1] = RD16(_b + (bnRow + 16 + frow)*128u + (XS)); \
    SET[2] = RD16(_b + (bnRow + 32 + frow)*128u + (XS)); \
    SET[3] = RD16(_b + (bnRow + 48 + frow)*128u + (XS)); } while (0)
#define STG_A(TSRC, BUFB, H) do { \
    const unsigned _rg = (BUFB) + (H)*16384u; \
    const __hip_bfloat16* _s = Ab + (size_t)(H)*128*KDIM + (size_t)(TSRC)*64; \
    async_load16(_s + ga0, smem + _rg + (unsigned)ch0*16u); \
    async_load16(_s + ga1, smem + _rg + (unsigned)ch1*16u); } while (0)
#define STG_B(TSRC, BUFB, H) do { \
    const unsigned _rg = (BUFB) + 32768u + (H)*16384u; \
    const __hip_bfloat16* _s = Bb + (size_t)(H)*128*KDIM + (size_t)(TSRC)*64; \
    async_load16(_s + ga0, smem + _rg + (unsigned)ch0*16u); \
    async_load16(_s + ga1, smem + _rg + (unsigned)ch1*16u); } while (0)
#define MF16(ASET, BSET, MB) do { \
    __builtin_amdgcn_s_setprio(1); \
    _Pragma("unroll") for (int _m = 0; _m < 4; ++_m) \
    _Pragma("unroll") for (int _n = 0; _n < 4; ++_n) \
        acc[(MB)+_m][_n] = __builtin_amdgcn_mfma_f32_16x16x32_bf16( \
            ASET[_m], BSET[_n], acc[(MB)+_m][_n], 0, 0, 0); \
    __builtin_amdgcn_s_setprio(0); } while (0)
#define DRAIN_LGKM asm volatile("s_waitcnt lgkmcnt(0)" ::: "memory")
#define WAIT_VM4   asm volatile("s_waitcnt vmcnt(4)" ::: "memory")
#define PH_BAR do { __builtin_amdgcn_sched_barrier(0); \
                    __builtin_amdgcn_s_barrier(); } while (0)

    // ---- prologue: stage K0 (4 halves) + B1 (2) + A1h0; wait K0; read quad0 ----
    STG_B(0, 0u, 0); STG_B(0, 0u, 1);
    STG_A(0, 0u, 0); STG_A(0, 0u, 1);
    STG_B(1, 65536u, 0); STG_B(1, 65536u, 1);
    STG_A(1, 65536u, 0);
    asm volatile("s_waitcnt vmcnt(6)" ::: "memory");
    PH_BAR;
    LDA4(arE, 0u, 0, xs0); LDB4(brE, 0u, xs0);   // quad 0: (t0, mh0, kk0)

#pragma unroll 1
    for (int i = 0; i < NITER; ++i) {
        const int tb = 2 * i + 1;
        const int tc = (2 * i + 2 < 32) ? 2 * i + 2 : 31;  // src clamp; dest buf0
        const int td = (2 * i + 3 < 32) ? 2 * i + 3 : 31;  // src clamp; dest buf1

        // ph1: load q=(ta,mh0,kk1); MFMA q=(ta,mh0,kk0)
        LDA4(arO, 0u, 0, xs1); LDB4(brO, 0u, xs1);
        STG_A(tb, 65536u, 1);
        MF16(arE, brE, 0);
        DRAIN_LGKM; PH_BAR;
        // ph2: load q=(ta,mh1,kk0); MFMA q=(ta,mh0,kk1)
        LDA4(arE, 0u, 1, xs0);
        STG_B(tc, 0u, 0);
        MF16(arO, brO, 0);
        PH_BAR;
        // ph3: load q=(ta,mh1,kk1); MFMA q=(ta,mh1,kk0)
        LDA4(arO, 0u, 1, xs1);
        STG_B(tc, 0u, 1);
        MF16(arE, brE, 4);
        DRAIN_LGKM; WAIT_VM4; PH_BAR;          // tb fully landed for ph4 reads
        // ph4: load q=(tb,mh0,kk0); MFMA q=(ta,mh1,kk1)
        LDA4(arE, 65536u, 0, xs0); LDB4(brE, 65536u, xs0);
        STG_A(tc, 0u, 0);
        MF16(arO, brO, 4);
        PH_BAR;
        // ph5: load q=(tb,mh0,kk1); MFMA q=(tb,mh0,kk0)
        LDA4(arO, 65536u, 0, xs1); LDB4(brO, 65536u, xs1);
        STG_A(tc, 0u, 1);
        MF16(arE, brE, 0);
        DRAIN_LGKM; PH_BAR;
        // ph6: load q=(tb,mh1,kk0); MFMA q=(tb,mh0,kk1)
        LDA4(arE, 65536u, 1, xs0);
        STG_B(td, 65536u, 0);
        MF16(arO, brO, 0);
        PH_BAR;
        // ph7: load q=(tb,mh1,kk1); MFMA q=(tb,mh1,kk0)
        LDA4(arO, 65536u, 1, xs1);
        STG_B(td, 65536u, 1);
        MF16(arE, brE, 4);
        DRAIN_LGKM; WAIT_VM4; PH_BAR;          // tc fully landed for ph8 reads
        // ph8: load q=(tc,mh0,kk0) [dummy at i=15]; MFMA q=(tb,mh1,kk1)
        LDA4(arE, 0u, 0, xs0); LDB4(brE, 0u, xs0);
        STG_A(td, 65536u, 0);
        MF16(arO, brO, 4);
        PH_BAR;
    }
#undef RD16
#undef LDA4
#undef LDB4
#undef STG_A
#undef STG_B
#undef MF16
#undef DRAIN_LGKM
#undef WAIT_VM4
#undef PH_BAR

    // ---- fused epilogue: gates lane-local thanks to B permutation ----
    const int j = bn * 64 + wn * 16 + (lane & 15);
    const float bf_ = Ub[j];
    const float bi_ = Ub[1024 + j];
    const float bo_ = Ub[2048 + j];
    const float bg_ = Ub[3072 + j];
    const int row0 = bm * BM + wm * 128 + ((lane >> 4) << 2);

    float cp[8][4];
#pragma unroll
    for (int m = 0; m < 8; ++m)
#pragma unroll
        for (int r = 0; r < 4; ++r)
            cp[m][r] = c_prev[(size_t)(row0 + m * 16 + r) * HID + j];

#pragma unroll
    for (int m = 0; m < 8; ++m) {
#pragma unroll
        for (int r = 0; r < 4; ++r) {
            const int row = row0 + m * 16 + r;
            const float f  = sigmoidf_(acc[m][0][r] + bf_);
            const float it = sigmoidf_(acc[m][1][r] + bi_);
            const float o  = sigmoidf_(acc[m][2][r] + bo_);
            const float gg = tanhf_(acc[m][3][r] + bg_);
            const float cv = f * cp[m][r] + it * gg;
            const float hv = o * tanhf_(cv);
            out[(size_t)row * HID + j] = hv;
            out[(size_t)BATCH * HID + (size_t)row * HID + j] = cv;
        }
    }
}

// ---------------------------------------------------------------------------
extern "C" void kernel_launch(void* const* d_in, const int* in_sizes, int n_in,
                              void* d_out, int out_size, void* d_ws, size_t ws_size,
                              hipStream_t stream) {
    const float* x      = (const float*)d_in[0];
    const float* h_prev = (const float*)d_in[1];
    const float* c_prev = (const float*)d_in[2];
    const float* U_w    = (const float*)d_in[3];
    const float* U_b    = (const float*)d_in[4];
    const float* W_w    = (const float*)d_in[5];
    float* out = (float*)d_out;

    char* ws = (char*)d_ws;
    __hip_bfloat16* Acat = (__hip_bfloat16*)ws;                      // 16 MB
    __hip_bfloat16* Bcat = (__hip_bfloat16*)(ws + (16u << 20));      // 16 MB

    convert_kernel<<<8192, 256, 0, stream>>>(x, h_prev, U_w, W_w, Acat, Bcat);
    gemm_lstm_kernel<<<256, 512, 0, stream>>>(Acat, Bcat, U_b, c_prev, out);
}